// Round 1
// baseline (674.405 us; speedup 1.0000x reference)
//
#include <hip/hip_runtime.h>
#include <math.h>

// ---------------- CSR build (counting sort by dst) ----------------

__global__ void k_init_counts(int* counts, int n) {
  int i = blockIdx.x * blockDim.x + threadIdx.x;
  if (i < n) counts[i] = 1;  // each node gets one self-loop
}

__global__ void k_hist(const int* __restrict__ dst, int E, int* counts) {
  int stride = gridDim.x * blockDim.x;
  for (int e = blockIdx.x * blockDim.x + threadIdx.x; e < E; e += stride)
    atomicAdd(&counts[dst[e]], 1);
}

__global__ void k_scan_block(const int* __restrict__ in, int* __restrict__ out,
                             int* __restrict__ sums, int n) {
  __shared__ int tmp[1024];
  int tid = threadIdx.x;
  int i = blockIdx.x * 1024 + tid;
  int v = (i < n) ? in[i] : 0;
  int x = v;
  tmp[tid] = x;
  __syncthreads();
  for (int off = 1; off < 1024; off <<= 1) {
    int y = (tid >= off) ? tmp[tid - off] : 0;
    __syncthreads();
    x += y;
    tmp[tid] = x;
    __syncthreads();
  }
  if (i < n) out[i] = x - v;            // exclusive within block
  if (tid == 1023) sums[blockIdx.x] = x; // block total
}

__global__ void k_scan_sums(int* sums, int nb) {
  if (blockIdx.x == 0 && threadIdx.x == 0) {
    int run = 0;
    for (int i = 0; i < nb; i++) { int v = sums[i]; sums[i] = run; run += v; }
  }
}

__global__ void k_add_back(int* __restrict__ row_ptr, int* __restrict__ cursor,
                           const int* __restrict__ sums, int n, int total) {
  int i = blockIdx.x * blockDim.x + threadIdx.x;
  if (i < n) {
    int v = row_ptr[i] + sums[i >> 10];
    row_ptr[i] = v;
    cursor[i] = v;
  }
  if (i == 0) row_ptr[n] = total;
}

__global__ void k_scatter(const int* __restrict__ src, const int* __restrict__ dst,
                          const float* __restrict__ ea, int E, int* cursor,
                          int* __restrict__ ssrc, float* __restrict__ sea) {
  int stride = gridDim.x * blockDim.x;
  for (int e = blockIdx.x * blockDim.x + threadIdx.x; e < E; e += stride) {
    int d = dst[e];
    int pos = atomicAdd(&cursor[d], 1);
    ssrc[pos] = src[e];
    sea[pos] = ea[e];
  }
}

__global__ void k_scatter_self(int n, int* cursor, int* __restrict__ ssrc,
                               float* __restrict__ sea) {
  int i = blockIdx.x * blockDim.x + threadIdx.x;
  if (i < n) {
    int pos = atomicAdd(&cursor[i], 1);
    ssrc[pos] = i;
    sea[pos] = 1.0f;
  }
}

// ---------------- node linear: xl = h@Wl+bl, xr = h@Wr+br ----------------

template<int CIN>
__global__ void k_lin2(const float* __restrict__ h,
                       const float* __restrict__ Wl, const float* __restrict__ bl,
                       const float* __restrict__ Wr, const float* __restrict__ br,
                       float* __restrict__ xl, float* __restrict__ xr, int N) {
  int t = blockIdx.x * blockDim.x + threadIdx.x;
  int row = t >> 7;   // 128 outputs per row (64 for xl, 64 for xr)
  if (row >= N) return;
  int j = t & 127;
  int c = j & 63;
  const float* W = (j < 64) ? Wl : Wr;
  float acc = (j < 64) ? bl[c] : br[c];
  const float* hr = h + (size_t)row * CIN;
  #pragma unroll
  for (int k = 0; k < CIN; k++) acc = fmaf(hr[k], W[k * 64 + c], acc);
  float* o = (j < 64) ? xl : xr;
  o[(size_t)row * 64 + c] = acc;
}

// ---------------- per-dst-node edge pass: online segment softmax + agg ----

__global__ void k_gat_edge(const float* __restrict__ xl, const float* __restrict__ xr,
                           const int* __restrict__ row_ptr, const int* __restrict__ ssrc,
                           const float* __restrict__ sea,
                           const float* __restrict__ We, const float* __restrict__ att,
                           const float* __restrict__ bias,
                           float* __restrict__ out, int N) {
  int gw = (blockIdx.x * blockDim.x + threadIdx.x) >> 6;  // one wave per node
  int lane = threadIdx.x & 63;                            // lane = channel
  if (gw >= N) return;
  int n = gw;
  float xi = xr[(size_t)n * 64 + lane];
  float wec = We[lane];
  float attc = att[lane];
  int e0 = row_ptr[n], e1 = row_ptr[n + 1];
  float m = -INFINITY, s = 0.f, acc = 0.f;
  for (int e = e0; e < e1; e++) {
    int sv = ssrc[e];
    float eav = sea[e];
    float xj = xl[(size_t)sv * 64 + lane];
    float z = xi + xj + eav * wec;
    z = (z > 0.f) ? z : 0.2f * z;
    float p = z * attc;
    #pragma unroll
    for (int off = 32; off; off >>= 1) p += __shfl_xor(p, off, 64);
    // online softmax update (all lanes hold the same m, s)
    if (p <= m) {
      float wgt = __expf(p - m);
      s += wgt;
      acc = fmaf(wgt, xj, acc);
    } else {
      float coef = __expf(m - p);   // m=-inf first iter -> coef=0
      s = fmaf(s, coef, 1.f);
      acc = fmaf(acc, coef, xj);
      m = p;
    }
  }
  out[(size_t)n * 64 + lane] = acc / s + bias[lane];
}

// ---------------- launch ----------------

extern "C" void kernel_launch(void* const* d_in, const int* in_sizes, int n_in,
                              void* d_out, int out_size, void* d_ws, size_t ws_size,
                              hipStream_t stream) {
  const float* x    = (const float*)d_in[0];
  const int*   ei   = (const int*)d_in[1];
  const float* ea   = (const float*)d_in[2];
  const float* Wl0  = (const float*)d_in[3];
  const float* bl0  = (const float*)d_in[4];
  const float* Wr0  = (const float*)d_in[5];
  const float* br0  = (const float*)d_in[6];
  const float* We0  = (const float*)d_in[7];
  const float* att0 = (const float*)d_in[8];
  const float* bias0= (const float*)d_in[9];
  const float* Wl1  = (const float*)d_in[10];
  const float* bl1  = (const float*)d_in[11];
  const float* Wr1  = (const float*)d_in[12];
  const float* br1  = (const float*)d_in[13];
  const float* We1  = (const float*)d_in[14];
  const float* att1 = (const float*)d_in[15];
  const float* bias1= (const float*)d_in[16];

  const int N  = in_sizes[0] / 128;
  const int E  = in_sizes[1] / 2;
  const int ET = E + N;
  const int* src = ei;
  const int* dst = ei + E;

  char* w = (char*)d_ws;
  float* xl      = (float*)w; w += (size_t)N * 64 * 4;
  float* xr      = (float*)w; w += (size_t)N * 64 * 4;
  float* h1      = (float*)w; w += (size_t)N * 64 * 4;
  int*   row_ptr = (int*)w;   w += (size_t)(N + 1) * 4;
  int*   cursor  = (int*)w;   w += (size_t)N * 4;     // doubles as counts
  int*   ssrc    = (int*)w;   w += (size_t)ET * 4;
  float* sea     = (float*)w; w += (size_t)ET * 4;
  int*   sums    = (int*)w;   w += 256;

  float* out = (float*)d_out;

  // ---- CSR build (same graph for both layers) ----
  int nb_scan = (N + 1023) / 1024;
  k_init_counts<<<(N + 255) / 256, 256, 0, stream>>>(cursor, N);
  k_hist<<<1024, 256, 0, stream>>>(dst, E, cursor);
  k_scan_block<<<nb_scan, 1024, 0, stream>>>(cursor, row_ptr, sums, N);
  k_scan_sums<<<1, 64, 0, stream>>>(sums, nb_scan);
  k_add_back<<<(N + 255) / 256, 256, 0, stream>>>(row_ptr, cursor, sums, N, ET);
  k_scatter<<<1024, 256, 0, stream>>>(src, dst, ea, E, cursor, ssrc, sea);
  k_scatter_self<<<(N + 255) / 256, 256, 0, stream>>>(N, cursor, ssrc, sea);

  // ---- layer 0: 128 -> 64 ----
  {
    long total = (long)N * 128;
    k_lin2<128><<<(int)((total + 255) / 256), 256, 0, stream>>>(x, Wl0, bl0, Wr0, br0, xl, xr, N);
    k_gat_edge<<<(N + 3) / 4, 256, 0, stream>>>(xl, xr, row_ptr, ssrc, sea, We0, att0, bias0, h1, N);
  }
  // ---- layer 1: 64 -> 64 ----
  {
    long total = (long)N * 128;
    k_lin2<64><<<(int)((total + 255) / 256), 256, 0, stream>>>(h1, Wl1, bl1, Wr1, br1, xl, xr, N);
    k_gat_edge<<<(N + 3) / 4, 256, 0, stream>>>(xl, xr, row_ptr, ssrc, sea, We1, att1, bias1, out, N);
  }
}

// Round 2
// 470.037 us; speedup vs baseline: 1.4348x; 1.4348x over previous
//
#include <hip/hip_runtime.h>
#include <math.h>

// ---------------- CSR build (counting sort by dst) ----------------

__global__ void k_init_counts(int* counts, int n) {
  int i = blockIdx.x * blockDim.x + threadIdx.x;
  if (i < n) counts[i] = 1;  // each node gets one self-loop
}

__global__ void k_hist(const int* __restrict__ dst, int E, int* counts) {
  int stride = gridDim.x * blockDim.x;
  for (int e = blockIdx.x * blockDim.x + threadIdx.x; e < E; e += stride)
    atomicAdd(&counts[dst[e]], 1);
}

__global__ void k_scan_block(const int* __restrict__ in, int* __restrict__ out,
                             int* __restrict__ sums, int n) {
  __shared__ int tmp[1024];
  int tid = threadIdx.x;
  int i = blockIdx.x * 1024 + tid;
  int v = (i < n) ? in[i] : 0;
  int x = v;
  tmp[tid] = x;
  __syncthreads();
  for (int off = 1; off < 1024; off <<= 1) {
    int y = (tid >= off) ? tmp[tid - off] : 0;
    __syncthreads();
    x += y;
    tmp[tid] = x;
    __syncthreads();
  }
  if (i < n) out[i] = x - v;            // exclusive within block
  if (tid == 1023) sums[blockIdx.x] = x; // block total
}

__global__ void k_scan_sums(int* sums, int nb) {
  if (blockIdx.x == 0 && threadIdx.x == 0) {
    int run = 0;
    for (int i = 0; i < nb; i++) { int v = sums[i]; sums[i] = run; run += v; }
  }
}

__global__ void k_add_back(int* __restrict__ row_ptr, int* __restrict__ cursor,
                           const int* __restrict__ sums, int n, int total) {
  int i = blockIdx.x * blockDim.x + threadIdx.x;
  if (i < n) {
    int v = row_ptr[i] + sums[i >> 10];
    row_ptr[i] = v;
    cursor[i] = v;
  }
  if (i == 0) row_ptr[n] = total;
}

__global__ void k_scatter(const int* __restrict__ src, const int* __restrict__ dst,
                          const float* __restrict__ ea, int E, int* cursor,
                          int* __restrict__ ssrc, float* __restrict__ sea) {
  int stride = gridDim.x * blockDim.x;
  for (int e = blockIdx.x * blockDim.x + threadIdx.x; e < E; e += stride) {
    int d = dst[e];
    int pos = atomicAdd(&cursor[d], 1);
    ssrc[pos] = src[e];
    sea[pos] = ea[e];
  }
}

__global__ void k_scatter_self(int n, int* cursor, int* __restrict__ ssrc,
                               float* __restrict__ sea) {
  int i = blockIdx.x * blockDim.x + threadIdx.x;
  if (i < n) {
    int pos = atomicAdd(&cursor[i], 1);
    ssrc[pos] = i;
    sea[pos] = 1.0f;
  }
}

// ---------------- node linear (LDS-tiled GEMM): [xl|xr] = h @ [Wl|Wr] + [bl|br]
// 64-row x 128-col tile per 256-thread block, K-tile = 64.
// Each thread: 8 rows x 4 cols register accumulator.

template<int CIN>
__global__ __launch_bounds__(256) void k_lin2_tiled(
    const float* __restrict__ h,
    const float* __restrict__ Wl, const float* __restrict__ bl,
    const float* __restrict__ Wr, const float* __restrict__ br,
    float* __restrict__ xl, float* __restrict__ xr, int N) {
  __shared__ float sW[64][128];  // 32 KB: K-tile x 128 combined cols
  __shared__ float sH[64][64];   // 16 KB: 64 rows x K-tile
  const int t = threadIdx.x;
  const int row0 = blockIdx.x * 64;
  const int c4 = (t & 31) * 4;   // this thread's 4 output cols (0..127)
  const int rr = (t >> 5) * 8;   // this thread's 8 output rows (0..63)

  float acc[8][4];
  #pragma unroll
  for (int r = 0; r < 8; r++)
    #pragma unroll
    for (int c = 0; c < 4; c++) acc[r][c] = 0.f;

  for (int kt = 0; kt < CIN; kt += 64) {
    __syncthreads();
    // stage W tile: 64 x 128 floats, coalesced float4
    #pragma unroll
    for (int i = 0; i < 8; i++) {
      int flat = i * 1024 + t * 4;
      int k = flat >> 7, j = flat & 127;
      const float* Wsrc = (j < 64) ? Wl : Wr;
      *(float4*)&sW[k][j] = *(const float4*)&Wsrc[(size_t)(kt + k) * 64 + (j & 63)];
    }
    // stage H tile: 64 rows x 64 k, coalesced float4
    #pragma unroll
    for (int i = 0; i < 4; i++) {
      int flat = i * 1024 + t * 4;
      int r = flat >> 6, k = flat & 63;
      float4 v = make_float4(0.f, 0.f, 0.f, 0.f);
      if (row0 + r < N) v = *(const float4*)&h[(size_t)(row0 + r) * CIN + kt + k];
      *(float4*)&sH[r][k] = v;
    }
    __syncthreads();
    #pragma unroll 8
    for (int k = 0; k < 64; k++) {
      float4 w = *(float4*)&sW[k][c4];          // ds_read_b128, stride-16B pattern
      #pragma unroll
      for (int r = 0; r < 8; r++) {
        float hv = sH[rr + r][k];               // LDS broadcast within half-wave
        acc[r][0] = fmaf(hv, w.x, acc[r][0]);
        acc[r][1] = fmaf(hv, w.y, acc[r][1]);
        acc[r][2] = fmaf(hv, w.z, acc[r][2]);
        acc[r][3] = fmaf(hv, w.w, acc[r][3]);
      }
    }
  }

  const float* bsrc = (c4 < 64) ? bl : br;
  float bv[4];
  #pragma unroll
  for (int c = 0; c < 4; c++) bv[c] = bsrc[(c4 & 63) + c];
  float* o = (c4 < 64) ? xl : xr;
  #pragma unroll
  for (int r = 0; r < 8; r++) {
    int row = row0 + rr + r;
    if (row < N) {
      float4 v = make_float4(acc[r][0] + bv[0], acc[r][1] + bv[1],
                             acc[r][2] + bv[2], acc[r][3] + bv[3]);
      *(float4*)&o[(size_t)row * 64 + (c4 & 63)] = v;
    }
  }
}

// ---------------- per-dst-node edge pass: online segment softmax + agg ----

__global__ void k_gat_edge(const float* __restrict__ xl, const float* __restrict__ xr,
                           const int* __restrict__ row_ptr, const int* __restrict__ ssrc,
                           const float* __restrict__ sea,
                           const float* __restrict__ We, const float* __restrict__ att,
                           const float* __restrict__ bias,
                           float* __restrict__ out, int N) {
  int gw = (blockIdx.x * blockDim.x + threadIdx.x) >> 6;  // one wave per node
  int lane = threadIdx.x & 63;                            // lane = channel
  if (gw >= N) return;
  int n = gw;
  float xi = xr[(size_t)n * 64 + lane];
  float wec = We[lane];
  float attc = att[lane];
  int e0 = row_ptr[n], e1 = row_ptr[n + 1];
  float m = -INFINITY, s = 0.f, acc = 0.f;
  for (int e = e0; e < e1; e++) {
    int sv = ssrc[e];
    float eav = sea[e];
    float xj = xl[(size_t)sv * 64 + lane];
    float z = xi + xj + eav * wec;
    z = (z > 0.f) ? z : 0.2f * z;
    float p = z * attc;
    #pragma unroll
    for (int off = 32; off; off >>= 1) p += __shfl_xor(p, off, 64);
    if (p <= m) {
      float wgt = __expf(p - m);
      s += wgt;
      acc = fmaf(wgt, xj, acc);
    } else {
      float coef = __expf(m - p);   // m=-inf first iter -> coef=0
      s = fmaf(s, coef, 1.f);
      acc = fmaf(acc, coef, xj);
      m = p;
    }
  }
  out[(size_t)n * 64 + lane] = acc / s + bias[lane];
}

// ---------------- launch ----------------

extern "C" void kernel_launch(void* const* d_in, const int* in_sizes, int n_in,
                              void* d_out, int out_size, void* d_ws, size_t ws_size,
                              hipStream_t stream) {
  const float* x    = (const float*)d_in[0];
  const int*   ei   = (const int*)d_in[1];
  const float* ea   = (const float*)d_in[2];
  const float* Wl0  = (const float*)d_in[3];
  const float* bl0  = (const float*)d_in[4];
  const float* Wr0  = (const float*)d_in[5];
  const float* br0  = (const float*)d_in[6];
  const float* We0  = (const float*)d_in[7];
  const float* att0 = (const float*)d_in[8];
  const float* bias0= (const float*)d_in[9];
  const float* Wl1  = (const float*)d_in[10];
  const float* bl1  = (const float*)d_in[11];
  const float* Wr1  = (const float*)d_in[12];
  const float* br1  = (const float*)d_in[13];
  const float* We1  = (const float*)d_in[14];
  const float* att1 = (const float*)d_in[15];
  const float* bias1= (const float*)d_in[16];

  const int N  = in_sizes[0] / 128;
  const int E  = in_sizes[1] / 2;
  const int ET = E + N;
  const int* src = ei;
  const int* dst = ei + E;

  char* w = (char*)d_ws;
  float* xl      = (float*)w; w += (size_t)N * 64 * 4;
  float* xr      = (float*)w; w += (size_t)N * 64 * 4;
  float* h1      = (float*)w; w += (size_t)N * 64 * 4;
  int*   row_ptr = (int*)w;   w += (size_t)(N + 1) * 4;
  int*   cursor  = (int*)w;   w += (size_t)N * 4;     // doubles as counts
  int*   ssrc    = (int*)w;   w += (size_t)ET * 4;
  float* sea     = (float*)w; w += (size_t)ET * 4;
  int*   sums    = (int*)w;   w += 256;

  float* out = (float*)d_out;

  // ---- CSR build (same graph for both layers) ----
  int nb_scan = (N + 1023) / 1024;
  k_init_counts<<<(N + 255) / 256, 256, 0, stream>>>(cursor, N);
  k_hist<<<1024, 256, 0, stream>>>(dst, E, cursor);
  k_scan_block<<<nb_scan, 1024, 0, stream>>>(cursor, row_ptr, sums, N);
  k_scan_sums<<<1, 64, 0, stream>>>(sums, nb_scan);
  k_add_back<<<(N + 255) / 256, 256, 0, stream>>>(row_ptr, cursor, sums, N, ET);
  k_scatter<<<1024, 256, 0, stream>>>(src, dst, ea, E, cursor, ssrc, sea);
  k_scatter_self<<<(N + 255) / 256, 256, 0, stream>>>(N, cursor, ssrc, sea);

  // ---- layer 0: 128 -> 64 ----
  {
    int nblk = (N + 63) / 64;
    k_lin2_tiled<128><<<nblk, 256, 0, stream>>>(x, Wl0, bl0, Wr0, br0, xl, xr, N);
    k_gat_edge<<<(N + 3) / 4, 256, 0, stream>>>(xl, xr, row_ptr, ssrc, sea, We0, att0, bias0, h1, N);
  }
  // ---- layer 1: 64 -> 64 ----
  {
    int nblk = (N + 63) / 64;
    k_lin2_tiled<64><<<nblk, 256, 0, stream>>>(h1, Wl1, bl1, Wr1, br1, xl, xr, N);
    k_gat_edge<<<(N + 3) / 4, 256, 0, stream>>>(xl, xr, row_ptr, ssrc, sea, We1, att1, bias1, out, N);
  }
}

// Round 3
// 296.319 us; speedup vs baseline: 2.2759x; 1.5863x over previous
//
#include <hip/hip_runtime.h>
#include <math.h>

// ---------------- CSR build (counting sort by dst) ----------------

__global__ void k_init_counts(int* counts, int n) {
  int i = blockIdx.x * blockDim.x + threadIdx.x;
  if (i < n) counts[i] = 1;  // each node gets one self-loop
}

__global__ void k_hist(const int* __restrict__ dst, int E, int* counts) {
  int stride = gridDim.x * blockDim.x;
  for (int e = blockIdx.x * blockDim.x + threadIdx.x; e < E; e += stride)
    atomicAdd(&counts[dst[e]], 1);
}

__global__ void k_scan_block(const int* __restrict__ in, int* __restrict__ out,
                             int* __restrict__ sums, int n) {
  __shared__ int tmp[1024];
  int tid = threadIdx.x;
  int i = blockIdx.x * 1024 + tid;
  int v = (i < n) ? in[i] : 0;
  int x = v;
  tmp[tid] = x;
  __syncthreads();
  for (int off = 1; off < 1024; off <<= 1) {
    int y = (tid >= off) ? tmp[tid - off] : 0;
    __syncthreads();
    x += y;
    tmp[tid] = x;
    __syncthreads();
  }
  if (i < n) out[i] = x - v;            // exclusive within block
  if (tid == 1023) sums[blockIdx.x] = x; // block total
}

__global__ void k_scan_sums(int* sums, int nb) {
  if (blockIdx.x == 0 && threadIdx.x == 0) {
    int run = 0;
    for (int i = 0; i < nb; i++) { int v = sums[i]; sums[i] = run; run += v; }
  }
}

__global__ void k_add_back(int* __restrict__ row_ptr, int* __restrict__ cursor,
                           const int* __restrict__ sums, int n, int total) {
  int i = blockIdx.x * blockDim.x + threadIdx.x;
  if (i < n) {
    int v = row_ptr[i] + sums[i >> 10];
    row_ptr[i] = v;
    cursor[i] = v;
  }
  if (i == 0) row_ptr[n] = total;
}

__global__ void k_scatter(const int* __restrict__ src, const int* __restrict__ dst,
                          const float* __restrict__ ea, int E, int* cursor,
                          int2* __restrict__ eidx) {
  int stride = gridDim.x * blockDim.x;
  for (int e = blockIdx.x * blockDim.x + threadIdx.x; e < E; e += stride) {
    int d = dst[e];
    int pos = atomicAdd(&cursor[d], 1);
    eidx[pos] = make_int2(src[e], __float_as_int(ea[e]));
  }
}

__global__ void k_scatter_self(int n, int* cursor, int2* __restrict__ eidx) {
  int i = blockIdx.x * blockDim.x + threadIdx.x;
  if (i < n) {
    int pos = atomicAdd(&cursor[i], 1);
    eidx[pos] = make_int2(i, __float_as_int(1.0f));
  }
}

// ---------------- node linear (LDS-tiled GEMM): [xl|xr] = h @ [Wl|Wr] + [bl|br]

template<int CIN>
__global__ __launch_bounds__(256) void k_lin2_tiled(
    const float* __restrict__ h,
    const float* __restrict__ Wl, const float* __restrict__ bl,
    const float* __restrict__ Wr, const float* __restrict__ br,
    float* __restrict__ xl, float* __restrict__ xr, int N) {
  __shared__ float sW[64][128];  // 32 KB
  __shared__ float sH[64][64];   // 16 KB
  const int t = threadIdx.x;
  const int row0 = blockIdx.x * 64;
  const int c4 = (t & 31) * 4;
  const int rr = (t >> 5) * 8;

  float acc[8][4];
  #pragma unroll
  for (int r = 0; r < 8; r++)
    #pragma unroll
    for (int c = 0; c < 4; c++) acc[r][c] = 0.f;

  for (int kt = 0; kt < CIN; kt += 64) {
    __syncthreads();
    #pragma unroll
    for (int i = 0; i < 8; i++) {
      int flat = i * 1024 + t * 4;
      int k = flat >> 7, j = flat & 127;
      const float* Wsrc = (j < 64) ? Wl : Wr;
      *(float4*)&sW[k][j] = *(const float4*)&Wsrc[(size_t)(kt + k) * 64 + (j & 63)];
    }
    #pragma unroll
    for (int i = 0; i < 4; i++) {
      int flat = i * 1024 + t * 4;
      int r = flat >> 6, k = flat & 63;
      float4 v = make_float4(0.f, 0.f, 0.f, 0.f);
      if (row0 + r < N) v = *(const float4*)&h[(size_t)(row0 + r) * CIN + kt + k];
      *(float4*)&sH[r][k] = v;
    }
    __syncthreads();
    #pragma unroll 8
    for (int k = 0; k < 64; k++) {
      float4 w = *(float4*)&sW[k][c4];
      #pragma unroll
      for (int r = 0; r < 8; r++) {
        float hv = sH[rr + r][k];
        acc[r][0] = fmaf(hv, w.x, acc[r][0]);
        acc[r][1] = fmaf(hv, w.y, acc[r][1]);
        acc[r][2] = fmaf(hv, w.z, acc[r][2]);
        acc[r][3] = fmaf(hv, w.w, acc[r][3]);
      }
    }
  }

  const float* bsrc = (c4 < 64) ? bl : br;
  float bv[4];
  #pragma unroll
  for (int c = 0; c < 4; c++) bv[c] = bsrc[(c4 & 63) + c];
  float* o = (c4 < 64) ? xl : xr;
  #pragma unroll
  for (int r = 0; r < 8; r++) {
    int row = row0 + rr + r;
    if (row < N) {
      float4 v = make_float4(acc[r][0] + bv[0], acc[r][1] + bv[1],
                             acc[r][2] + bv[2], acc[r][3] + bv[3]);
      *(float4*)&o[(size_t)row * 64 + (c4 & 63)] = v;
    }
  }
}

// ---------------- per-dst-node edge pass: 4 edges/wave, online segment softmax
// lane = (group g = lane>>4, sub = lane&15); lane holds channels sub*4..sub*4+3.
// Group g processes edges e0+g, e0+g+4, ... with its own online (m,s,acc) state;
// states merged across groups at the end via shfl_xor 16/32.

__global__ __launch_bounds__(256) void k_gat_edge(
    const float* __restrict__ xl, const float* __restrict__ xr,
    const int* __restrict__ row_ptr, const int2* __restrict__ eidx,
    const float* __restrict__ We, const float* __restrict__ att,
    const float* __restrict__ bias,
    float* __restrict__ out, int N) {
  int n = (blockIdx.x * blockDim.x + threadIdx.x) >> 6;  // one wave per node
  if (n >= N) return;
  int lane = threadIdx.x & 63;
  int g = lane >> 4;
  int cb = (lane & 15) * 4;

  float4 xi = *(const float4*)&xr[(size_t)n * 64 + cb];
  float4 we = *(const float4*)&We[cb];
  float4 at = *(const float4*)&att[cb];

  int e0 = row_ptr[n], e1 = row_ptr[n + 1];

  float m = -INFINITY, s = 0.f;
  float4 acc = make_float4(0.f, 0.f, 0.f, 0.f);

  int e = e0 + g;
  int2 meta = make_int2(0, 0);
  float4 xj = make_float4(0.f, 0.f, 0.f, 0.f);
  if (e < e1) {
    meta = eidx[e];
    xj = *(const float4*)&xl[(size_t)meta.x * 64 + cb];
  }

  while (e < e1) {
    int2 cm = meta;
    float4 cxj = xj;
    int en = e + 4;
    if (en < e1) {  // prefetch next edge for this group
      meta = eidx[en];
      xj = *(const float4*)&xl[(size_t)meta.x * 64 + cb];
    }
    float eav = __int_as_float(cm.y);
    // z = leaky_relu(xi + xj + eav*We)
    float4 z;
    z.x = xi.x + cxj.x + eav * we.x;
    z.y = xi.y + cxj.y + eav * we.y;
    z.z = xi.z + cxj.z + eav * we.z;
    z.w = xi.w + cxj.w + eav * we.w;
    z.x = fmaxf(z.x, 0.f) + 0.2f * fminf(z.x, 0.f);
    z.y = fmaxf(z.y, 0.f) + 0.2f * fminf(z.y, 0.f);
    z.z = fmaxf(z.z, 0.f) + 0.2f * fminf(z.z, 0.f);
    z.w = fmaxf(z.w, 0.f) + 0.2f * fminf(z.w, 0.f);
    float p = z.x * at.x + z.y * at.y + z.z * at.z + z.w * at.w;
    // reduce over the 16 lanes of this group
    #pragma unroll
    for (int off = 1; off < 16; off <<= 1) p += __shfl_xor(p, off, 64);
    // branchless online softmax update (uniform within group)
    float mn = fmaxf(m, p);
    float cs = __expf(m - mn);    // m=-inf first iter -> 0
    float cp = __expf(p - mn);
    s = s * cs + cp;
    acc.x = acc.x * cs + cp * cxj.x;
    acc.y = acc.y * cs + cp * cxj.y;
    acc.z = acc.z * cs + cp * cxj.z;
    acc.w = acc.w * cs + cp * cxj.w;
    m = mn;
    e = en;
  }

  // merge the 4 group states (channels aligned: lane^16 / lane^32 hold same cb)
  #pragma unroll
  for (int off = 16; off <= 32; off <<= 1) {
    float mo = __shfl_xor(m, off, 64);
    float so = __shfl_xor(s, off, 64);
    float4 ao;
    ao.x = __shfl_xor(acc.x, off, 64);
    ao.y = __shfl_xor(acc.y, off, 64);
    ao.z = __shfl_xor(acc.z, off, 64);
    ao.w = __shfl_xor(acc.w, off, 64);
    float mn = fmaxf(m, mo);
    float cs = (m == -INFINITY) ? 0.f : __expf(m - mn);
    float co = (mo == -INFINITY) ? 0.f : __expf(mo - mn);
    s = s * cs + so * co;
    acc.x = acc.x * cs + ao.x * co;
    acc.y = acc.y * cs + ao.y * co;
    acc.z = acc.z * cs + ao.z * co;
    acc.w = acc.w * cs + ao.w * co;
    m = mn;
  }

  if (g == 0) {  // lanes 0..15 hold the full merged state; one store per wave
    float inv = 1.0f / s;
    float4 o;
    o.x = acc.x * inv + bias[cb + 0];
    o.y = acc.y * inv + bias[cb + 1];
    o.z = acc.z * inv + bias[cb + 2];
    o.w = acc.w * inv + bias[cb + 3];
    *(float4*)&out[(size_t)n * 64 + cb] = o;
  }
}

// ---------------- launch ----------------

extern "C" void kernel_launch(void* const* d_in, const int* in_sizes, int n_in,
                              void* d_out, int out_size, void* d_ws, size_t ws_size,
                              hipStream_t stream) {
  const float* x    = (const float*)d_in[0];
  const int*   ei   = (const int*)d_in[1];
  const float* ea   = (const float*)d_in[2];
  const float* Wl0  = (const float*)d_in[3];
  const float* bl0  = (const float*)d_in[4];
  const float* Wr0  = (const float*)d_in[5];
  const float* br0  = (const float*)d_in[6];
  const float* We0  = (const float*)d_in[7];
  const float* att0 = (const float*)d_in[8];
  const float* bias0= (const float*)d_in[9];
  const float* Wl1  = (const float*)d_in[10];
  const float* bl1  = (const float*)d_in[11];
  const float* Wr1  = (const float*)d_in[12];
  const float* br1  = (const float*)d_in[13];
  const float* We1  = (const float*)d_in[14];
  const float* att1 = (const float*)d_in[15];
  const float* bias1= (const float*)d_in[16];

  const int N  = in_sizes[0] / 128;
  const int E  = in_sizes[1] / 2;
  const int ET = E + N;
  const int* src = ei;
  const int* dst = ei + E;

  char* w = (char*)d_ws;
  float* xl      = (float*)w; w += (size_t)N * 64 * 4;
  float* xr      = (float*)w; w += (size_t)N * 64 * 4;
  float* h1      = (float*)w; w += (size_t)N * 64 * 4;
  int*   row_ptr = (int*)w;   w += (size_t)(N + 2) * 4;  // padded for 8B alignment
  int*   cursor  = (int*)w;   w += (size_t)N * 4;
  int2*  eidx    = (int2*)w;  w += (size_t)ET * 8;
  int*   sums    = (int*)w;   w += 256;

  float* out = (float*)d_out;

  // ---- CSR build (same graph for both layers) ----
  int nb_scan = (N + 1023) / 1024;
  k_init_counts<<<(N + 255) / 256, 256, 0, stream>>>(cursor, N);
  k_hist<<<1024, 256, 0, stream>>>(dst, E, cursor);
  k_scan_block<<<nb_scan, 1024, 0, stream>>>(cursor, row_ptr, sums, N);
  k_scan_sums<<<1, 64, 0, stream>>>(sums, nb_scan);
  k_add_back<<<(N + 255) / 256, 256, 0, stream>>>(row_ptr, cursor, sums, N, ET);
  k_scatter<<<1024, 256, 0, stream>>>(src, dst, ea, E, cursor, eidx);
  k_scatter_self<<<(N + 255) / 256, 256, 0, stream>>>(N, cursor, eidx);

  // ---- layer 0: 128 -> 64 ----
  {
    int nblk = (N + 63) / 64;
    k_lin2_tiled<128><<<nblk, 256, 0, stream>>>(x, Wl0, bl0, Wr0, br0, xl, xr, N);
    k_gat_edge<<<(N + 3) / 4, 256, 0, stream>>>(xl, xr, row_ptr, eidx, We0, att0, bias0, h1, N);
  }
  // ---- layer 1: 64 -> 64 ----
  {
    int nblk = (N + 63) / 64;
    k_lin2_tiled<64><<<nblk, 256, 0, stream>>>(h1, Wl1, bl1, Wr1, br1, xl, xr, N);
    k_gat_edge<<<(N + 3) / 4, 256, 0, stream>>>(xl, xr, row_ptr, eidx, We1, att1, bias1, out, N);
  }
}